// Round 1
// baseline (1995.567 us; speedup 1.0000x reference)
//
#include <hip/hip_runtime.h>

#define NWIN 2048
#define TPB 256

typedef __attribute__((ext_vector_type(8))) short short8;
typedef __attribute__((ext_vector_type(4))) float floatx4;

__device__ __forceinline__ float bf2f(unsigned short u) {
    union { unsigned int i; float f; } v; v.i = ((unsigned int)u) << 16; return v.f;
}
__device__ __forceinline__ unsigned short f2bf(float f) {
    union { float f; unsigned int i; } v; v.f = f;
    unsigned int u = v.i;
    return (unsigned short)((u + 0x7FFFu + ((u >> 16) & 1u)) >> 16);
}
__device__ __forceinline__ floatx4 mfma16(short8 a, short8 b, floatx4 c) {
    return __builtin_amdgcn_mfma_f32_16x16x32_bf16(a, b, c, 0, 0, 0);
}

// ---------------- K0: convert all weights/biases fp32 -> bf16 in ws --------
__global__ __launch_bounds__(TPB) void k0_cvt(
    const float* __restrict__ inw, const float* __restrict__ inb,
    const float* __restrict__ outw, const float* __restrict__ outb,
    const float* __restrict__ n1w, const float* __restrict__ n1b,
    const float* __restrict__ n2w, const float* __restrict__ n2b,
    const float* __restrict__ w1, const float* __restrict__ b1,
    const float* __restrict__ w2, const float* __restrict__ b2,
    unsigned short* __restrict__ dst)
{
    int i = blockIdx.x * TPB + threadIdx.x;
    if (i >= 1183872) return;
    const float* src; int off;
    if      (i < 442368)  { src = inw;  off = 0; }
    else if (i < 443520)  { src = inb;  off = 442368; }
    else if (i < 590976)  { src = outw; off = 443520; }
    else if (i < 591360)  { src = outb; off = 590976; }
    else if (i < 591744)  { src = n1w;  off = 591360; }
    else if (i < 592128)  { src = n1b;  off = 591744; }
    else if (i < 592512)  { src = n2w;  off = 592128; }
    else if (i < 592896)  { src = n2b;  off = 592512; }
    else if (i < 887808)  { src = w1;   off = 592896; }
    else if (i < 888576)  { src = b1;   off = 887808; }
    else if (i < 1183488) { src = w2;   off = 888576; }
    else                  { src = b2;   off = 1183488; }
    dst[i] = f2bf(src[i - off]);
}

// ---------------- K1: window partition + LayerNorm1 -> y (bf16) ------------
__global__ __launch_bounds__(TPB) void k1_ln1(
    const float* __restrict__ x,
    const unsigned short* __restrict__ n1w,
    const unsigned short* __restrict__ n1b,
    unsigned short* __restrict__ ybuf)
{
    __shared__ __align__(16) unsigned short win[64][392];
    __shared__ float mu_s[64], rs_s[64];
    const int tid = threadIdx.x;
    const int widx = blockIdx.x;
    const int b = widx >> 8, nh = (widx >> 4) & 15, nw = widx & 15;
    const size_t xbase = (size_t)b * 384 * 16384 + (size_t)nh * 8 * 128 + (size_t)nw * 8;

    for (int idx = tid; idx < 6144; idx += TPB) {
        int c = idx >> 4, i = (idx >> 1) & 7, half = idx & 1;
        floatx4 v = *(const floatx4*)(x + xbase + (size_t)c * 16384 + i * 128 + half * 4);
        #pragma unroll
        for (int j = 0; j < 4; ++j) win[i * 8 + half * 4 + j][c] = f2bf(v[j]);
    }
    __syncthreads();
    {
        int row = tid >> 2, part = tid & 3;
        float s = 0.f, sq = 0.f;
        for (int c = part * 96; c < part * 96 + 96; ++c) {
            float f = bf2f(win[row][c]); s += f; sq += f * f;
        }
        s += __shfl_xor(s, 1); s += __shfl_xor(s, 2);
        sq += __shfl_xor(sq, 1); sq += __shfl_xor(sq, 2);
        float mu = s * (1.f / 384.f);
        float var = sq * (1.f / 384.f) - mu * mu;
        if (part == 0) { mu_s[row] = mu; rs_s[row] = rsqrtf(var + 1e-5f); }
    }
    __syncthreads();
    const size_t ybase = (size_t)widx * 24576;
    for (int idx = tid; idx < 3072; idx += TPB) {
        int r = idx / 48, c0 = (idx % 48) * 8;
        float mu = mu_s[r], rs = rs_s[r];
        short8 o;
        #pragma unroll
        for (int j = 0; j < 8; ++j) {
            int c = c0 + j;
            o[j] = (short)f2bf((bf2f(win[r][c]) - mu) * rs * bf2f(n1w[c]) + bf2f(n1b[c]));
        }
        *(short8*)(ybuf + ybase + idx * 8) = o;
    }
}

// ---------------- K2: fused attention per window (y -> o, same ws region) ---
__global__ __launch_bounds__(TPB) void k2_attn(
    unsigned short* __restrict__ yo,
    const unsigned short* __restrict__ in_w,
    const unsigned short* __restrict__ in_b)
{
    __shared__ __align__(16) unsigned short ylds[24576];
    __shared__ __align__(16) unsigned short aux[7552];
    const int tid = threadIdx.x;
    const int wave = tid >> 6, lane = tid & 63;
    const int l15 = lane & 15, lg = lane >> 4;
    const int widx = blockIdx.x;
    const size_t base = (size_t)widx * 24576;
    const short8 z8 = {0, 0, 0, 0, 0, 0, 0, 0};

    for (int g = tid; g < 3072; g += TPB) {
        int m = g / 48, kc = g % 48;
        short8 v = *(const short8*)(yo + base + g * 8);
        *(short8*)&ylds[m * 384 + ((kc ^ (m & 7)) << 3)] = v;
    }
    __syncthreads();
    const float scale = 0.14433756729740643f;  // 1/sqrt(48)

    for (int h = 0; h < 8; ++h) {
        // ---- Phase 1: Q and K tiles
        {
            floatx4 acc[6];
            #pragma unroll
            for (int i = 0; i < 6; ++i) acc[i] = (floatx4){0, 0, 0, 0};
            const int m = wave * 16 + l15;
            #pragma unroll 1
            for (int ks = 0; ks < 12; ++ks) {
                int kc = ks * 4 + lg;
                short8 a = *(const short8*)&ylds[m * 384 + ((kc ^ (m & 7)) << 3)];
                #pragma unroll
                for (int sel = 0; sel < 2; ++sel) {
                    #pragma unroll
                    for (int nt = 0; nt < 3; ++nt) {
                        int f = sel * 384 + h * 48 + nt * 16 + l15;
                        short8 bb = *(const short8*)(in_w + (size_t)f * 384 + ks * 32 + lg * 8);
                        acc[sel * 3 + nt] = mfma16(a, bb, acc[sel * 3 + nt]);
                    }
                }
            }
            #pragma unroll
            for (int sel = 0; sel < 2; ++sel) {
                #pragma unroll
                for (int nt = 0; nt < 3; ++nt) {
                    int d = nt * 16 + l15;
                    float bias = bf2f(in_b[sel * 384 + h * 48 + d]);
                    #pragma unroll
                    for (int r = 0; r < 4; ++r) {
                        int mm = wave * 16 + lg * 4 + r;
                        aux[sel * 3584 + mm * 56 + d] = f2bf(acc[sel * 3 + nt][r] + bias);
                    }
                }
            }
        }
        __syncthreads();
        // ---- Phase 2: S = Q K^T
        floatx4 sacc[4];
        #pragma unroll
        for (int i = 0; i < 4; ++i) sacc[i] = (floatx4){0, 0, 0, 0};
        {
            const int mq = wave * 16 + l15;
            short8 a0 = *(const short8*)&aux[mq * 56 + lg * 8];
            #pragma unroll
            for (int nt = 0; nt < 4; ++nt) {
                short8 bb = *(const short8*)&aux[3584 + (nt * 16 + l15) * 56 + lg * 8];
                sacc[nt] = mfma16(a0, bb, sacc[nt]);
            }
            short8 a1 = (lg < 2) ? *(const short8*)&aux[mq * 56 + 32 + lg * 8] : z8;
            #pragma unroll
            for (int nt = 0; nt < 4; ++nt) {
                short8 bb = (lg < 2) ? *(const short8*)&aux[3584 + (nt * 16 + l15) * 56 + 32 + lg * 8] : z8;
                sacc[nt] = mfma16(a1, bb, sacc[nt]);
            }
        }
        __syncthreads();
        // ---- Phase 3: softmax -> p ; V GEMM -> vt
        {
            #pragma unroll
            for (int r = 0; r < 4; ++r) {
                float mx = fmaxf(fmaxf(sacc[0][r], sacc[1][r]), fmaxf(sacc[2][r], sacc[3][r]));
                mx = fmaxf(mx, __shfl_xor(mx, 1));
                mx = fmaxf(mx, __shfl_xor(mx, 2));
                mx = fmaxf(mx, __shfl_xor(mx, 4));
                mx = fmaxf(mx, __shfl_xor(mx, 8));
                float e[4];
                #pragma unroll
                for (int nt = 0; nt < 4; ++nt) e[nt] = __expf(scale * (sacc[nt][r] - mx));
                float sm = e[0] + e[1] + e[2] + e[3];
                sm += __shfl_xor(sm, 1); sm += __shfl_xor(sm, 2);
                sm += __shfl_xor(sm, 4); sm += __shfl_xor(sm, 8);
                float inv = 1.f / sm;
                int row = wave * 16 + lg * 4 + r;
                int rs = row & 7;
                #pragma unroll
                for (int nt = 0; nt < 4; ++nt) {
                    int tc = nt * 2 + (l15 >> 3);
                    aux[row * 64 + ((tc ^ rs) << 3) + (l15 & 7)] = f2bf(e[nt] * inv);
                }
            }
            floatx4 vacc[3];
            #pragma unroll
            for (int i = 0; i < 3; ++i) vacc[i] = (floatx4){0, 0, 0, 0};
            const int m = wave * 16 + l15;
            #pragma unroll 1
            for (int ks = 0; ks < 12; ++ks) {
                int kc = ks * 4 + lg;
                short8 a = *(const short8*)&ylds[m * 384 + ((kc ^ (m & 7)) << 3)];
                #pragma unroll
                for (int nt = 0; nt < 3; ++nt) {
                    int f = 768 + h * 48 + nt * 16 + l15;
                    short8 bb = *(const short8*)(in_w + (size_t)f * 384 + ks * 32 + lg * 8);
                    vacc[nt] = mfma16(a, bb, vacc[nt]);
                }
            }
            #pragma unroll
            for (int nt = 0; nt < 3; ++nt) {
                int d = nt * 16 + l15;
                float bias = bf2f(in_b[768 + h * 48 + d]);
                #pragma unroll
                for (int r = 0; r < 4; ++r) {
                    int t = wave * 16 + lg * 4 + r;
                    aux[4096 + d * 72 + t] = f2bf(vacc[nt][r] + bias);  // v transposed [d][t]
                }
            }
        }
        __syncthreads();
        // ---- Phase 4: O_h = P V -> ws (overwrite y region, cols h*48..)
        {
            floatx4 oacc[3];
            #pragma unroll
            for (int i = 0; i < 3; ++i) oacc[i] = (floatx4){0, 0, 0, 0};
            const int m = wave * 16 + l15;
            #pragma unroll
            for (int ks = 0; ks < 2; ++ks) {
                int kc = ks * 4 + lg;
                short8 a = *(const short8*)&aux[m * 64 + ((kc ^ (m & 7)) << 3)];
                #pragma unroll
                for (int nt = 0; nt < 3; ++nt) {
                    short8 bb = *(const short8*)&aux[4096 + (nt * 16 + l15) * 72 + ks * 32 + lg * 8];
                    oacc[nt] = mfma16(a, bb, oacc[nt]);
                }
            }
            #pragma unroll
            for (int nt = 0; nt < 3; ++nt) {
                #pragma unroll
                for (int r = 0; r < 4; ++r) {
                    int mm = wave * 16 + lg * 4 + r;
                    yo[base + (size_t)mm * 384 + h * 48 + nt * 16 + l15] = f2bf(oacc[nt][r]);
                }
            }
        }
        __syncthreads();
    }
}

// ---------------- K3: out-proj + residual (o -> win2, same ws region) -------
__global__ __launch_bounds__(TPB) void k3_proj(
    const float* __restrict__ x,
    unsigned short* __restrict__ ow,
    const unsigned short* __restrict__ out_w,
    const unsigned short* __restrict__ out_b)
{
    __shared__ __align__(16) unsigned short olds[24576];
    const int tid = threadIdx.x;
    const int wave = tid >> 6, lane = tid & 63;
    const int l15 = lane & 15, lg = lane >> 4;
    const int widx = blockIdx.x;
    const int b = widx >> 8, nh = (widx >> 4) & 15, nw = widx & 15;
    const size_t base = (size_t)widx * 24576;
    const size_t xbase = (size_t)b * 384 * 16384 + (size_t)nh * 8 * 128 + (size_t)nw * 8;

    for (int g = tid; g < 3072; g += TPB) {
        int m = g / 48, kc = g % 48;
        short8 v = *(const short8*)(ow + base + g * 8);
        *(short8*)&olds[m * 384 + ((kc ^ (m & 7)) << 3)] = v;
    }
    __syncthreads();

    floatx4 acc[24];
    #pragma unroll
    for (int i = 0; i < 24; ++i) acc[i] = (floatx4){0, 0, 0, 0};
    #pragma unroll 1
    for (int ks = 0; ks < 12; ++ks) {
        short8 a[4];
        #pragma unroll
        for (int mt = 0; mt < 4; ++mt) {
            int m = mt * 16 + l15;
            int kc = ks * 4 + lg;
            a[mt] = *(const short8*)&olds[m * 384 + ((kc ^ (m & 7)) << 3)];
        }
        #pragma unroll
        for (int nt = 0; nt < 6; ++nt) {
            int f = wave * 96 + nt * 16 + l15;
            short8 bb = *(const short8*)(out_w + (size_t)f * 384 + ks * 32 + lg * 8);
            #pragma unroll
            for (int mt = 0; mt < 4; ++mt)
                acc[nt * 4 + mt] = mfma16(a[mt], bb, acc[nt * 4 + mt]);
        }
    }
    #pragma unroll
    for (int nt = 0; nt < 6; ++nt) {
        int col = wave * 96 + nt * 16 + l15;
        float bias = bf2f(out_b[col]);
        #pragma unroll
        for (int mt = 0; mt < 4; ++mt) {
            #pragma unroll
            for (int r = 0; r < 4; ++r) {
                int m = mt * 16 + lg * 4 + r;
                int i = m >> 3, j = m & 7;
                float res = x[xbase + (size_t)col * 16384 + i * 128 + j];
                ow[base + (size_t)m * 384 + col] = f2bf(acc[nt * 4 + mt][r] + bias + res);
            }
        }
    }
}

// ---------------- K4: LN2 + full MLP + residual, in-place window-major ------
// 512 threads, 8 waves. LDS: ylds 64x392 (50,176 B) + hlds 64x776 (99,328 B).
// fc1: wave owns 96 hidden cols x 64 tokens. fc2: wave owns 48 out cols.
__global__ __launch_bounds__(512) void k4_mlp(
    unsigned short* __restrict__ wbuf,          // win2 in -> final res out (in-place)
    const unsigned short* __restrict__ n2w,
    const unsigned short* __restrict__ n2b,
    const unsigned short* __restrict__ w1,
    const unsigned short* __restrict__ b1,
    const unsigned short* __restrict__ w2,
    const unsigned short* __restrict__ b2)
{
    __shared__ __align__(16) unsigned short ylds[64][392];
    __shared__ __align__(16) unsigned short hlds[64][776];
    const int tid = threadIdx.x;
    const int wave = tid >> 6, lane = tid & 63;
    const int l15 = lane & 15, lg = lane >> 4;
    const int widx = blockIdx.x;
    const size_t base = (size_t)widx * 24576;

    {   // LN2: 8 threads per row, 48 cols each
        int row = tid >> 3, part = tid & 7;
        const unsigned short* src = wbuf + base + row * 384 + part * 48;
        float s = 0.f, sq = 0.f;
        #pragma unroll
        for (int g = 0; g < 6; ++g) {
            short8 v = *(const short8*)(src + g * 8);
            #pragma unroll
            for (int j = 0; j < 8; ++j) { float f = bf2f((unsigned short)v[j]); s += f; sq += f * f; }
        }
        s += __shfl_xor(s, 1); s += __shfl_xor(s, 2); s += __shfl_xor(s, 4);
        sq += __shfl_xor(sq, 1); sq += __shfl_xor(sq, 2); sq += __shfl_xor(sq, 4);
        float mu = s * (1.f / 384.f);
        float rs = rsqrtf(sq * (1.f / 384.f) - mu * mu + 1e-5f);
        #pragma unroll
        for (int g = 0; g < 6; ++g) {
            short8 v = *(const short8*)(src + g * 8);
            short8 o;
            #pragma unroll
            for (int j = 0; j < 8; ++j) {
                int c = part * 48 + g * 8 + j;
                o[j] = (short)f2bf((bf2f((unsigned short)v[j]) - mu) * rs * bf2f(n2w[c]) + bf2f(n2b[c]));
            }
            *(short8*)&ylds[row][part * 48 + g * 8] = o;
        }
    }
    __syncthreads();

    {   // fc1 + GELU -> hlds
        floatx4 acc[24];
        #pragma unroll
        for (int i = 0; i < 24; ++i) acc[i] = (floatx4){0, 0, 0, 0};
        #pragma unroll 1
        for (int ks = 0; ks < 12; ++ks) {
            short8 a[4];
            #pragma unroll
            for (int mt = 0; mt < 4; ++mt)
                a[mt] = *(const short8*)&ylds[mt * 16 + l15][ks * 32 + lg * 8];
            #pragma unroll
            for (int nt = 0; nt < 6; ++nt) {
                int f = wave * 96 + nt * 16 + l15;
                short8 bb = *(const short8*)(w1 + (size_t)f * 384 + ks * 32 + lg * 8);
                #pragma unroll
                for (int mt = 0; mt < 4; ++mt)
                    acc[nt * 4 + mt] = mfma16(a[mt], bb, acc[nt * 4 + mt]);
            }
        }
        #pragma unroll
        for (int nt = 0; nt < 6; ++nt) {
            int col = wave * 96 + nt * 16 + l15;
            float bias = bf2f(b1[col]);
            #pragma unroll
            for (int mt = 0; mt < 4; ++mt) {
                #pragma unroll
                for (int r = 0; r < 4; ++r) {
                    float v = acc[nt * 4 + mt][r] + bias;
                    float g = 0.5f * v * (1.f + erff(v * 0.70710678118654752f));
                    hlds[mt * 16 + lg * 4 + r][col] = f2bf(g);
                }
            }
        }
    }
    __syncthreads();

    {   // fc2 (K=768 from hlds) + b2 + residual, write back in place
        floatx4 acc2[12];
        #pragma unroll
        for (int i = 0; i < 12; ++i) acc2[i] = (floatx4){0, 0, 0, 0};
        #pragma unroll 1
        for (int ks = 0; ks < 24; ++ks) {
            short8 a[4];
            #pragma unroll
            for (int mt = 0; mt < 4; ++mt)
                a[mt] = *(const short8*)&hlds[mt * 16 + l15][ks * 32 + lg * 8];
            #pragma unroll
            for (int nt = 0; nt < 3; ++nt) {
                int c = wave * 48 + nt * 16 + l15;
                short8 bb = *(const short8*)(w2 + (size_t)c * 768 + ks * 32 + lg * 8);
                #pragma unroll
                for (int mt = 0; mt < 4; ++mt)
                    acc2[nt * 4 + mt] = mfma16(a[mt], bb, acc2[nt * 4 + mt]);
            }
        }
        #pragma unroll
        for (int nt = 0; nt < 3; ++nt) {
            int col = wave * 48 + nt * 16 + l15;
            float bias = bf2f(b2[col]);
            #pragma unroll
            for (int mt = 0; mt < 4; ++mt) {
                #pragma unroll
                for (int r = 0; r < 4; ++r) {
                    int mm = mt * 16 + lg * 4 + r;
                    float res = bf2f(wbuf[base + (size_t)mm * 384 + col]);
                    wbuf[base + (size_t)mm * 384 + col] = f2bf(acc2[nt * 4 + mt][r] + bias + res);
                }
            }
        }
    }
}

// ---------------- K5: window reverse, bf16 window-major -> fp32 [b,c,h,w] ---
// Block = (b, nh, i, ch): 16 nw x 8 j x 192 c. Full 512B row stores.
__global__ __launch_bounds__(TPB) void k5_out(
    const unsigned short* __restrict__ res,
    float* __restrict__ out)
{
    __shared__ __align__(16) unsigned short t[128][200];
    const int tid = threadIdx.x;
    const int bid = blockIdx.x;
    const int ch = bid & 1, i = (bid >> 1) & 7, nh = (bid >> 4) & 15, b = bid >> 8;

    {   // load: 2 threads per (nw,j) row, 12 chunks of 8 each
        int wrow = tid >> 1, half = tid & 1;
        int nw = wrow >> 3, j = wrow & 7;
        size_t rbase = (size_t)(((b * 16 + nh) * 16) + nw) * 24576 + (i * 8 + j) * 384 + ch * 192;
        #pragma unroll
        for (int g = 0; g < 12; ++g) {
            int cc = half * 12 + g;
            short8 v = *(const short8*)(res + rbase + cc * 8);
            *(short8*)&t[wrow][cc * 8] = v;
        }
    }
    __syncthreads();
    {   // store: per iter, 8 c-values x 32 w-groups of 4
        int q = tid >> 5, wg = tid & 31;
        int w0 = wg * 4;
        size_t obase = ((size_t)b * 384 + ch * 192) * 16384 + (size_t)(nh * 8 + i) * 128 + w0;
        #pragma unroll 1
        for (int cc = 0; cc < 24; ++cc) {
            int cp = cc * 8 + q;
            floatx4 v;
            #pragma unroll
            for (int k = 0; k < 4; ++k) v[k] = bf2f(t[w0 + k][cp]);
            *(floatx4*)(out + obase + (size_t)cp * 16384) = v;
        }
    }
}

extern "C" void kernel_launch(void* const* d_in, const int* in_sizes, int n_in,
                              void* d_out, int out_size, void* d_ws, size_t ws_size,
                              hipStream_t stream) {
    (void)in_sizes; (void)n_in; (void)out_size; (void)ws_size;
    const float* x    = (const float*)d_in[0];
    const float* n1w  = (const float*)d_in[1];
    const float* n1b  = (const float*)d_in[2];
    const float* inw  = (const float*)d_in[3];
    const float* inb  = (const float*)d_in[4];
    const float* outw = (const float*)d_in[5];
    const float* outb = (const float*)d_in[6];
    const float* n2w  = (const float*)d_in[7];
    const float* n2b  = (const float*)d_in[8];
    const float* w1   = (const float*)d_in[9];
    const float* b1   = (const float*)d_in[10];
    const float* w2   = (const float*)d_in[11];
    const float* b2   = (const float*)d_in[12];
    unsigned short* wsu  = (unsigned short*)d_ws;
    unsigned short* ybuf = wsu;                      // 50,331,648 elems (win-major)
    unsigned short* wb   = wsu + 50331648;           // bf16 weights, 1,183,872 elems
    const unsigned short* inw_b  = wb;
    const unsigned short* inb_b  = wb + 442368;
    const unsigned short* outw_b = wb + 443520;
    const unsigned short* outb_b = wb + 590976;
    const unsigned short* n1w_b  = wb + 591360;
    const unsigned short* n1b_b  = wb + 591744;
    const unsigned short* n2w_b  = wb + 592128;
    const unsigned short* n2b_b  = wb + 592512;
    const unsigned short* w1_b   = wb + 592896;
    const unsigned short* b1_b   = wb + 887808;
    const unsigned short* w2_b   = wb + 888576;
    const unsigned short* b2_b   = wb + 1183488;
    float* out = (float*)d_out;

    k0_cvt<<<dim3((1183872 + TPB - 1) / TPB), dim3(TPB), 0, stream>>>(
        inw, inb, outw, outb, n1w, n1b, n2w, n2b, w1, b1, w2, b2, wb);
    k1_ln1<<<dim3(NWIN), dim3(TPB), 0, stream>>>(x, n1w_b, n1b_b, ybuf);
    k2_attn<<<dim3(NWIN), dim3(TPB), 0, stream>>>(ybuf, inw_b, inb_b);
    k3_proj<<<dim3(NWIN), dim3(TPB), 0, stream>>>(x, ybuf, outw_b, outb_b);
    k4_mlp<<<dim3(NWIN), dim3(512), 0, stream>>>(ybuf, n2w_b, n2b_b, w1_b, b1_b, w2_b, b2_b);
    k5_out<<<dim3(NWIN), dim3(TPB), 0, stream>>>(ybuf, out);
}

// Round 2
// 1423.143 us; speedup vs baseline: 1.4022x; 1.4022x over previous
//
#include <hip/hip_runtime.h>

#define NWIN 2048
#define TPB 256

typedef __attribute__((ext_vector_type(8))) short short8;
typedef __attribute__((ext_vector_type(4))) float floatx4;

__device__ __forceinline__ float bf2f(unsigned short u) {
    union { unsigned int i; float f; } v; v.i = ((unsigned int)u) << 16; return v.f;
}
__device__ __forceinline__ unsigned short f2bf(float f) {
    union { float f; unsigned int i; } v; v.f = f;
    unsigned int u = v.i;
    return (unsigned short)((u + 0x7FFFu + ((u >> 16) & 1u)) >> 16);
}
__device__ __forceinline__ floatx4 mfma16(short8 a, short8 b, floatx4 c) {
    return __builtin_amdgcn_mfma_f32_16x16x32_bf16(a, b, c, 0, 0, 0);
}

// ---------------- K0: convert all weights/biases fp32 -> bf16 in ws --------
__global__ __launch_bounds__(TPB) void k0_cvt(
    const float* __restrict__ inw, const float* __restrict__ inb,
    const float* __restrict__ outw, const float* __restrict__ outb,
    const float* __restrict__ n1w, const float* __restrict__ n1b,
    const float* __restrict__ n2w, const float* __restrict__ n2b,
    const float* __restrict__ w1, const float* __restrict__ b1,
    const float* __restrict__ w2, const float* __restrict__ b2,
    unsigned short* __restrict__ dst)
{
    int i = blockIdx.x * TPB + threadIdx.x;
    if (i >= 1183872) return;
    const float* src; int off;
    if      (i < 442368)  { src = inw;  off = 0; }
    else if (i < 443520)  { src = inb;  off = 442368; }
    else if (i < 590976)  { src = outw; off = 443520; }
    else if (i < 591360)  { src = outb; off = 590976; }
    else if (i < 591744)  { src = n1w;  off = 591360; }
    else if (i < 592128)  { src = n1b;  off = 591744; }
    else if (i < 592512)  { src = n2w;  off = 592128; }
    else if (i < 592896)  { src = n2b;  off = 592512; }
    else if (i < 887808)  { src = w1;   off = 592896; }
    else if (i < 888576)  { src = b1;   off = 887808; }
    else if (i < 1183488) { src = w2;   off = 888576; }
    else                  { src = b2;   off = 1183488; }
    dst[i] = f2bf(src[i - off]);
}

// ---------------- K1: window partition + LayerNorm1 -> y (bf16) ------------
__global__ __launch_bounds__(TPB) void k1_ln1(
    const float* __restrict__ x,
    const unsigned short* __restrict__ n1w,
    const unsigned short* __restrict__ n1b,
    unsigned short* __restrict__ ybuf)
{
    __shared__ __align__(16) unsigned short win[64][392];
    __shared__ float mu_s[64], rs_s[64];
    const int tid = threadIdx.x;
    const int widx = blockIdx.x;
    const int b = widx >> 8, nh = (widx >> 4) & 15, nw = widx & 15;
    const size_t xbase = (size_t)b * 384 * 16384 + (size_t)nh * 8 * 128 + (size_t)nw * 8;

    for (int idx = tid; idx < 6144; idx += TPB) {
        int c = idx >> 4, i = (idx >> 1) & 7, half = idx & 1;
        floatx4 v = *(const floatx4*)(x + xbase + (size_t)c * 16384 + i * 128 + half * 4);
        #pragma unroll
        for (int j = 0; j < 4; ++j) win[i * 8 + half * 4 + j][c] = f2bf(v[j]);
    }
    __syncthreads();
    {
        int row = tid >> 2, part = tid & 3;
        float s = 0.f, sq = 0.f;
        for (int c = part * 96; c < part * 96 + 96; ++c) {
            float f = bf2f(win[row][c]); s += f; sq += f * f;
        }
        s += __shfl_xor(s, 1); s += __shfl_xor(s, 2);
        sq += __shfl_xor(sq, 1); sq += __shfl_xor(sq, 2);
        float mu = s * (1.f / 384.f);
        float var = sq * (1.f / 384.f) - mu * mu;
        if (part == 0) { mu_s[row] = mu; rs_s[row] = rsqrtf(var + 1e-5f); }
    }
    __syncthreads();
    const size_t ybase = (size_t)widx * 24576;
    for (int idx = tid; idx < 3072; idx += TPB) {
        int r = idx / 48, c0 = (idx % 48) * 8;
        float mu = mu_s[r], rs = rs_s[r];
        short8 o;
        #pragma unroll
        for (int j = 0; j < 8; ++j) {
            int c = c0 + j;
            o[j] = (short)f2bf((bf2f(win[r][c]) - mu) * rs * bf2f(n1w[c]) + bf2f(n1b[c]));
        }
        *(short8*)(ybuf + ybase + idx * 8) = o;
    }
}

// ---------------- K2: fused attention, wave h owns head h end-to-end -------
// 512 threads = 8 waves. LDS: ylds 48KB + 8 x 12KB per-wave scratch = 144KB.
// One barrier total (after y staging); everything else is per-wave private.
__global__ __launch_bounds__(512) void k2_attn(
    unsigned short* __restrict__ yo,
    const unsigned short* __restrict__ in_w,
    const unsigned short* __restrict__ in_b)
{
    __shared__ __align__(16) unsigned short ylds[24576];
    __shared__ __align__(16) unsigned short wbuf[8][6144];
    const int tid = threadIdx.x;
    const int h = tid >> 6, lane = tid & 63;
    const int l15 = lane & 15, lg = lane >> 4;
    const int widx = blockIdx.x;
    const size_t base = (size_t)widx * 24576;
    const short8 z8 = {0, 0, 0, 0, 0, 0, 0, 0};

    unsigned short* bufA = &wbuf[h][0];     // Q [64][48] swz -> P halves [64][32] swz
    unsigned short* bufB = &wbuf[h][3072];  // K [64][48] swz -> V^T [48][64] swz

    for (int g = tid; g < 3072; g += 512) {
        int m = g / 48, kc = g % 48;
        short8 v = *(const short8*)(yo + base + g * 8);
        *(short8*)&ylds[m * 384 + ((kc ^ (m & 7)) << 3)] = v;
    }
    __syncthreads();

    const float scale = 0.14433756729740643f;  // 1/sqrt(48)
    const unsigned short* wq = in_w + (size_t)(h * 48) * 384;
    const unsigned short* wk = in_w + (size_t)(384 + h * 48) * 384;
    const unsigned short* wv = in_w + (size_t)(768 + h * 48) * 384;

    // ---- Q,K projection (64x48 each, K=384), into per-wave LDS ----
    {
        floatx4 acc[4][6];
        #pragma unroll
        for (int mt = 0; mt < 4; ++mt)
            #pragma unroll
            for (int i = 0; i < 6; ++i) acc[mt][i] = (floatx4){0, 0, 0, 0};
        #pragma unroll 1
        for (int ks = 0; ks < 12; ++ks) {
            short8 a[4];
            #pragma unroll
            for (int mt = 0; mt < 4; ++mt) {
                int m = mt * 16 + l15;
                a[mt] = *(const short8*)&ylds[m * 384 + (((ks * 4 + lg) ^ (m & 7)) << 3)];
            }
            #pragma unroll
            for (int nt = 0; nt < 3; ++nt) {
                short8 bq = *(const short8*)(wq + (size_t)(nt * 16 + l15) * 384 + ks * 32 + lg * 8);
                #pragma unroll
                for (int mt = 0; mt < 4; ++mt) acc[mt][nt] = mfma16(a[mt], bq, acc[mt][nt]);
                short8 bk = *(const short8*)(wk + (size_t)(nt * 16 + l15) * 384 + ks * 32 + lg * 8);
                #pragma unroll
                for (int mt = 0; mt < 4; ++mt) acc[mt][3 + nt] = mfma16(a[mt], bk, acc[mt][3 + nt]);
            }
        }
        #pragma unroll
        for (int sel = 0; sel < 2; ++sel) {
            unsigned short* dst = sel ? bufB : bufA;
            #pragma unroll
            for (int nt = 0; nt < 3; ++nt) {
                int d = nt * 16 + l15;
                int g = d >> 3;
                float bias = bf2f(in_b[sel * 384 + h * 48 + d]);
                #pragma unroll
                for (int mt = 0; mt < 4; ++mt)
                    #pragma unroll
                    for (int r = 0; r < 4; ++r) {
                        int mm = mt * 16 + lg * 4 + r;
                        dst[mm * 48 + ((g ^ (mm & 1)) << 3) + (d & 7)] =
                            f2bf(acc[mt][sel * 3 + nt][r] + bias);
                    }
            }
        }
    }

    // ---- S = Q K^T (16 tiles, K=48 padded to 64 with zero-guarded chunk) ---
    floatx4 sacc[4][4];
    #pragma unroll
    for (int mt = 0; mt < 4; ++mt)
        #pragma unroll
        for (int nt = 0; nt < 4; ++nt) sacc[mt][nt] = (floatx4){0, 0, 0, 0};
    {
        short8 b0[4], b1[4];
        #pragma unroll
        for (int nt = 0; nt < 4; ++nt) {
            int n = nt * 16 + l15;
            b0[nt] = *(const short8*)&bufB[n * 48 + ((lg ^ (n & 1)) << 3)];
            b1[nt] = (lg < 2) ? *(const short8*)&bufB[n * 48 + (((4 + lg) ^ (n & 1)) << 3)] : z8;
        }
        #pragma unroll
        for (int mt = 0; mt < 4; ++mt) {
            int mq = mt * 16 + l15;
            short8 a0 = *(const short8*)&bufA[mq * 48 + ((lg ^ (mq & 1)) << 3)];
            #pragma unroll
            for (int nt = 0; nt < 4; ++nt) sacc[mt][nt] = mfma16(a0, b0[nt], sacc[mt][nt]);
            short8 a1 = (lg < 2) ? *(const short8*)&bufA[mq * 48 + (((4 + lg) ^ (mq & 1)) << 3)] : z8;
            #pragma unroll
            for (int nt = 0; nt < 4; ++nt) sacc[mt][nt] = mfma16(a1, b1[nt], sacc[mt][nt]);
        }
    }

    // ---- softmax, fully in-register (row = mt*16 + lg*4 + r) ----
    #pragma unroll
    for (int mt = 0; mt < 4; ++mt)
        #pragma unroll
        for (int r = 0; r < 4; ++r) {
            float mx = fmaxf(fmaxf(sacc[mt][0][r], sacc[mt][1][r]),
                             fmaxf(sacc[mt][2][r], sacc[mt][3][r]));
            mx = fmaxf(mx, __shfl_xor(mx, 1));
            mx = fmaxf(mx, __shfl_xor(mx, 2));
            mx = fmaxf(mx, __shfl_xor(mx, 4));
            mx = fmaxf(mx, __shfl_xor(mx, 8));
            float e[4];
            #pragma unroll
            for (int nt = 0; nt < 4; ++nt) e[nt] = __expf(scale * (sacc[mt][nt][r] - mx));
            float sm = e[0] + e[1] + e[2] + e[3];
            sm += __shfl_xor(sm, 1); sm += __shfl_xor(sm, 2);
            sm += __shfl_xor(sm, 4); sm += __shfl_xor(sm, 8);
            float inv = 1.f / sm;
            #pragma unroll
            for (int nt = 0; nt < 4; ++nt) sacc[mt][nt][r] = e[nt] * inv;
        }

    // ---- store P half 0 (key cols 0..31) into bufA (Q is dead) ----
    #pragma unroll
    for (int mt = 0; mt < 4; ++mt)
        #pragma unroll
        for (int r = 0; r < 4; ++r) {
            int row = mt * 16 + lg * 4 + r;
            #pragma unroll
            for (int ntl = 0; ntl < 2; ++ntl) {
                int lc = ntl * 16 + l15;
                bufA[row * 32 + (((lc >> 3) ^ (row & 3)) << 3) + (lc & 7)] =
                    f2bf(sacc[mt][ntl][r]);
            }
        }

    // ---- V projection ----
    floatx4 vacc[4][3];
    #pragma unroll
    for (int mt = 0; mt < 4; ++mt)
        #pragma unroll
        for (int nt = 0; nt < 3; ++nt) vacc[mt][nt] = (floatx4){0, 0, 0, 0};
    #pragma unroll 1
    for (int ks = 0; ks < 12; ++ks) {
        short8 a[4];
        #pragma unroll
        for (int mt = 0; mt < 4; ++mt) {
            int m = mt * 16 + l15;
            a[mt] = *(const short8*)&ylds[m * 384 + (((ks * 4 + lg) ^ (m & 7)) << 3)];
        }
        #pragma unroll
        for (int nt = 0; nt < 3; ++nt) {
            short8 bv = *(const short8*)(wv + (size_t)(nt * 16 + l15) * 384 + ks * 32 + lg * 8);
            #pragma unroll
            for (int mt = 0; mt < 4; ++mt) vacc[mt][nt] = mfma16(a[mt], bv, vacc[mt][nt]);
        }
    }
    // V^T [48][64] swizzled into bufB (K is dead)
    #pragma unroll
    for (int nt = 0; nt < 3; ++nt) {
        int d = nt * 16 + l15;
        float bias = bf2f(in_b[768 + h * 48 + d]);
        #pragma unroll
        for (int mt = 0; mt < 4; ++mt)
            #pragma unroll
            for (int r = 0; r < 4; ++r) {
                int t = mt * 16 + lg * 4 + r;
                bufB[d * 64 + (((t >> 3) ^ (d & 7)) << 3) + (t & 7)] =
                    f2bf(vacc[mt][nt][r] + bias);
            }
    }

    // ---- O = P V (K=64 in two 32-wide halves; P half 1 stored mid-loop) ----
    floatx4 oacc[4][3];
    #pragma unroll
    for (int mt = 0; mt < 4; ++mt)
        #pragma unroll
        for (int nt = 0; nt < 3; ++nt) oacc[mt][nt] = (floatx4){0, 0, 0, 0};
    #pragma unroll
    for (int kh = 0; kh < 2; ++kh) {
        if (kh == 1) {
            #pragma unroll
            for (int mt = 0; mt < 4; ++mt)
                #pragma unroll
                for (int r = 0; r < 4; ++r) {
                    int row = mt * 16 + lg * 4 + r;
                    #pragma unroll
                    for (int ntl = 0; ntl < 2; ++ntl) {
                        int lc = ntl * 16 + l15;
                        bufA[row * 32 + (((lc >> 3) ^ (row & 3)) << 3) + (lc & 7)] =
                            f2bf(sacc[mt][2 + ntl][r]);
                    }
                }
        }
        #pragma unroll
        for (int mt = 0; mt < 4; ++mt) {
            int m = mt * 16 + l15;
            short8 a = *(const short8*)&bufA[m * 32 + ((lg ^ (m & 3)) << 3)];
            #pragma unroll
            for (int nt = 0; nt < 3; ++nt) {
                int d = nt * 16 + l15;
                int tg = kh * 4 + lg;
                short8 bb = *(const short8*)&bufB[d * 64 + ((tg ^ (d & 7)) << 3)];
                oacc[mt][nt] = mfma16(a, bb, oacc[mt][nt]);
            }
        }
    }
    // ---- write O columns h*48 .. h*48+47 ----
    #pragma unroll
    for (int nt = 0; nt < 3; ++nt)
        #pragma unroll
        for (int mt = 0; mt < 4; ++mt)
            #pragma unroll
            for (int r = 0; r < 4; ++r) {
                int mm = mt * 16 + lg * 4 + r;
                yo[base + (size_t)mm * 384 + h * 48 + nt * 16 + l15] = f2bf(oacc[mt][nt][r]);
            }
}

// ---------------- K3: out-proj + residual (o -> win2, same ws region) -------
__global__ __launch_bounds__(TPB) void k3_proj(
    const float* __restrict__ x,
    unsigned short* __restrict__ ow,
    const unsigned short* __restrict__ out_w,
    const unsigned short* __restrict__ out_b)
{
    __shared__ __align__(16) unsigned short olds[24576];
    const int tid = threadIdx.x;
    const int wave = tid >> 6, lane = tid & 63;
    const int l15 = lane & 15, lg = lane >> 4;
    const int widx = blockIdx.x;
    const int b = widx >> 8, nh = (widx >> 4) & 15, nw = widx & 15;
    const size_t base = (size_t)widx * 24576;
    const size_t xbase = (size_t)b * 384 * 16384 + (size_t)nh * 8 * 128 + (size_t)nw * 8;

    for (int g = tid; g < 3072; g += TPB) {
        int m = g / 48, kc = g % 48;
        short8 v = *(const short8*)(ow + base + g * 8);
        *(short8*)&olds[m * 384 + ((kc ^ (m & 7)) << 3)] = v;
    }
    __syncthreads();

    floatx4 acc[24];
    #pragma unroll
    for (int i = 0; i < 24; ++i) acc[i] = (floatx4){0, 0, 0, 0};
    #pragma unroll 1
    for (int ks = 0; ks < 12; ++ks) {
        short8 a[4];
        #pragma unroll
        for (int mt = 0; mt < 4; ++mt) {
            int m = mt * 16 + l15;
            int kc = ks * 4 + lg;
            a[mt] = *(const short8*)&olds[m * 384 + ((kc ^ (m & 7)) << 3)];
        }
        #pragma unroll
        for (int nt = 0; nt < 6; ++nt) {
            int f = wave * 96 + nt * 16 + l15;
            short8 bb = *(const short8*)(out_w + (size_t)f * 384 + ks * 32 + lg * 8);
            #pragma unroll
            for (int mt = 0; mt < 4; ++mt)
                acc[nt * 4 + mt] = mfma16(a[mt], bb, acc[nt * 4 + mt]);
        }
    }
    #pragma unroll
    for (int nt = 0; nt < 6; ++nt) {
        int col = wave * 96 + nt * 16 + l15;
        float bias = bf2f(out_b[col]);
        #pragma unroll
        for (int mt = 0; mt < 4; ++mt) {
            #pragma unroll
            for (int r = 0; r < 4; ++r) {
                int m = mt * 16 + lg * 4 + r;
                int i = m >> 3, j = m & 7;
                float res = x[xbase + (size_t)col * 16384 + i * 128 + j];
                ow[base + (size_t)m * 384 + col] = f2bf(acc[nt * 4 + mt][r] + bias + res);
            }
        }
    }
}

// ---------------- K4: LN2 + full MLP + residual, in-place window-major ------
__global__ __launch_bounds__(512) void k4_mlp(
    unsigned short* __restrict__ wbuf,
    const unsigned short* __restrict__ n2w,
    const unsigned short* __restrict__ n2b,
    const unsigned short* __restrict__ w1,
    const unsigned short* __restrict__ b1,
    const unsigned short* __restrict__ w2,
    const unsigned short* __restrict__ b2)
{
    __shared__ __align__(16) unsigned short ylds[64][392];
    __shared__ __align__(16) unsigned short hlds[64][776];
    const int tid = threadIdx.x;
    const int wave = tid >> 6, lane = tid & 63;
    const int l15 = lane & 15, lg = lane >> 4;
    const int widx = blockIdx.x;
    const size_t base = (size_t)widx * 24576;

    {   // LN2: 8 threads per row, 48 cols each
        int row = tid >> 3, part = tid & 7;
        const unsigned short* src = wbuf + base + row * 384 + part * 48;
        float s = 0.f, sq = 0.f;
        #pragma unroll
        for (int g = 0; g < 6; ++g) {
            short8 v = *(const short8*)(src + g * 8);
            #pragma unroll
            for (int j = 0; j < 8; ++j) { float f = bf2f((unsigned short)v[j]); s += f; sq += f * f; }
        }
        s += __shfl_xor(s, 1); s += __shfl_xor(s, 2); s += __shfl_xor(s, 4);
        sq += __shfl_xor(sq, 1); sq += __shfl_xor(sq, 2); sq += __shfl_xor(sq, 4);
        float mu = s * (1.f / 384.f);
        float rs = rsqrtf(sq * (1.f / 384.f) - mu * mu + 1e-5f);
        #pragma unroll
        for (int g = 0; g < 6; ++g) {
            short8 v = *(const short8*)(src + g * 8);
            short8 o;
            #pragma unroll
            for (int j = 0; j < 8; ++j) {
                int c = part * 48 + g * 8 + j;
                o[j] = (short)f2bf((bf2f((unsigned short)v[j]) - mu) * rs * bf2f(n2w[c]) + bf2f(n2b[c]));
            }
            *(short8*)&ylds[row][part * 48 + g * 8] = o;
        }
    }
    __syncthreads();

    {   // fc1 + GELU -> hlds
        floatx4 acc[24];
        #pragma unroll
        for (int i = 0; i < 24; ++i) acc[i] = (floatx4){0, 0, 0, 0};
        #pragma unroll 1
        for (int ks = 0; ks < 12; ++ks) {
            short8 a[4];
            #pragma unroll
            for (int mt = 0; mt < 4; ++mt)
                a[mt] = *(const short8*)&ylds[mt * 16 + l15][ks * 32 + lg * 8];
            #pragma unroll
            for (int nt = 0; nt < 6; ++nt) {
                int f = wave * 96 + nt * 16 + l15;
                short8 bb = *(const short8*)(w1 + (size_t)f * 384 + ks * 32 + lg * 8);
                #pragma unroll
                for (int mt = 0; mt < 4; ++mt)
                    acc[nt * 4 + mt] = mfma16(a[mt], bb, acc[nt * 4 + mt]);
            }
        }
        #pragma unroll
        for (int nt = 0; nt < 6; ++nt) {
            int col = wave * 96 + nt * 16 + l15;
            float bias = bf2f(b1[col]);
            #pragma unroll
            for (int mt = 0; mt < 4; ++mt) {
                #pragma unroll
                for (int r = 0; r < 4; ++r) {
                    float v = acc[nt * 4 + mt][r] + bias;
                    float g = 0.5f * v * (1.f + erff(v * 0.70710678118654752f));
                    hlds[mt * 16 + lg * 4 + r][col] = f2bf(g);
                }
            }
        }
    }
    __syncthreads();

    {   // fc2 (K=768 from hlds) + b2 + residual, write back in place
        floatx4 acc2[12];
        #pragma unroll
        for (int i = 0; i < 12; ++i) acc2[i] = (floatx4){0, 0, 0, 0};
        #pragma unroll 1
        for (int ks = 0; ks < 24; ++ks) {
            short8 a[4];
            #pragma unroll
            for (int mt = 0; mt < 4; ++mt)
                a[mt] = *(const short8*)&hlds[mt * 16 + l15][ks * 32 + lg * 8];
            #pragma unroll
            for (int nt = 0; nt < 3; ++nt) {
                int c = wave * 48 + nt * 16 + l15;
                short8 bb = *(const short8*)(w2 + (size_t)c * 768 + ks * 32 + lg * 8);
                #pragma unroll
                for (int mt = 0; mt < 4; ++mt)
                    acc2[nt * 4 + mt] = mfma16(a[mt], bb, acc2[nt * 4 + mt]);
            }
        }
        #pragma unroll
        for (int nt = 0; nt < 3; ++nt) {
            int col = wave * 48 + nt * 16 + l15;
            float bias = bf2f(b2[col]);
            #pragma unroll
            for (int mt = 0; mt < 4; ++mt) {
                #pragma unroll
                for (int r = 0; r < 4; ++r) {
                    int mm = mt * 16 + lg * 4 + r;
                    float res = bf2f(wbuf[base + (size_t)mm * 384 + col]);
                    wbuf[base + (size_t)mm * 384 + col] = f2bf(acc2[nt * 4 + mt][r] + bias + res);
                }
            }
        }
    }
}

// ---------------- K5: window reverse, bf16 window-major -> fp32 [b,c,h,w] ---
__global__ __launch_bounds__(TPB) void k5_out(
    const unsigned short* __restrict__ res,
    float* __restrict__ out)
{
    __shared__ __align__(16) unsigned short t[128][200];
    const int tid = threadIdx.x;
    const int bid = blockIdx.x;
    const int ch = bid & 1, i = (bid >> 1) & 7, nh = (bid >> 4) & 15, b = bid >> 8;

    {
        int wrow = tid >> 1, half = tid & 1;
        int nw = wrow >> 3, j = wrow & 7;
        size_t rbase = (size_t)(((b * 16 + nh) * 16) + nw) * 24576 + (i * 8 + j) * 384 + ch * 192;
        #pragma unroll
        for (int g = 0; g < 12; ++g) {
            int cc = half * 12 + g;
            short8 v = *(const short8*)(res + rbase + cc * 8);
            *(short8*)&t[wrow][cc * 8] = v;
        }
    }
    __syncthreads();
    {
        int q = tid >> 5, wg = tid & 31;
        int w0 = wg * 4;
        size_t obase = ((size_t)b * 384 + ch * 192) * 16384 + (size_t)(nh * 8 + i) * 128 + w0;
        #pragma unroll 1
        for (int cc = 0; cc < 24; ++cc) {
            int cp = cc * 8 + q;
            floatx4 v;
            #pragma unroll
            for (int k = 0; k < 4; ++k) v[k] = bf2f(t[w0 + k][cp]);
            *(floatx4*)(out + obase + (size_t)cp * 16384) = v;
        }
    }
}

extern "C" void kernel_launch(void* const* d_in, const int* in_sizes, int n_in,
                              void* d_out, int out_size, void* d_ws, size_t ws_size,
                              hipStream_t stream) {
    (void)in_sizes; (void)n_in; (void)out_size; (void)ws_size;
    const float* x    = (const float*)d_in[0];
    const float* n1w  = (const float*)d_in[1];
    const float* n1b  = (const float*)d_in[2];
    const float* inw  = (const float*)d_in[3];
    const float* inb  = (const float*)d_in[4];
    const float* outw = (const float*)d_in[5];
    const float* outb = (const float*)d_in[6];
    const float* n2w  = (const float*)d_in[7];
    const float* n2b  = (const float*)d_in[8];
    const float* w1   = (const float*)d_in[9];
    const float* b1   = (const float*)d_in[10];
    const float* w2   = (const float*)d_in[11];
    const float* b2   = (const float*)d_in[12];
    unsigned short* wsu  = (unsigned short*)d_ws;
    unsigned short* ybuf = wsu;                      // win-major activations
    unsigned short* wb   = wsu + 50331648;           // bf16 weights
    const unsigned short* inw_b  = wb;
    const unsigned short* inb_b  = wb + 442368;
    const unsigned short* outw_b = wb + 443520;
    const unsigned short* outb_b = wb + 590976;
    const unsigned short* n1w_b  = wb + 591360;
    const unsigned short* n1b_b  = wb + 591744;
    const unsigned short* n2w_b  = wb + 592128;
    const unsigned short* n2b_b  = wb + 592512;
    const unsigned short* w1_b   = wb + 592896;
    const unsigned short* b1_b   = wb + 887808;
    const unsigned short* w2_b   = wb + 888576;
    const unsigned short* b2_b   = wb + 1183488;
    float* out = (float*)d_out;

    k0_cvt<<<dim3((1183872 + TPB - 1) / TPB), dim3(TPB), 0, stream>>>(
        inw, inb, outw, outb, n1w, n1b, n2w, n2b, w1, b1, w2, b2, wb);
    k1_ln1<<<dim3(NWIN), dim3(TPB), 0, stream>>>(x, n1w_b, n1b_b, ybuf);
    k2_attn<<<dim3(NWIN), dim3(512), 0, stream>>>(ybuf, inw_b, inb_b);
    k3_proj<<<dim3(NWIN), dim3(TPB), 0, stream>>>(x, ybuf, outw_b, outb_b);
    k4_mlp<<<dim3(NWIN), dim3(512), 0, stream>>>(ybuf, n2w_b, n2b_b, w1_b, b1_b, w2_b, b2_b);
    k5_out<<<dim3(NWIN), dim3(TPB), 0, stream>>>(ybuf, out);
}

// Round 3
// 1322.856 us; speedup vs baseline: 1.5085x; 1.0758x over previous
//
#include <hip/hip_runtime.h>

#define NWIN 2048
#define TPB 256

typedef __attribute__((ext_vector_type(8))) short short8;
typedef __attribute__((ext_vector_type(4))) float floatx4;

__device__ __forceinline__ float bf2f(unsigned short u) {
    union { unsigned int i; float f; } v; v.i = ((unsigned int)u) << 16; return v.f;
}
__device__ __forceinline__ unsigned short f2bf(float f) {
    union { float f; unsigned int i; } v; v.f = f;
    unsigned int u = v.i;
    return (unsigned short)((u + 0x7FFFu + ((u >> 16) & 1u)) >> 16);
}
__device__ __forceinline__ floatx4 mfma16(short8 a, short8 b, floatx4 c) {
    return __builtin_amdgcn_mfma_f32_16x16x32_bf16(a, b, c, 0, 0, 0);
}

// ---------------- K0: convert all weights/biases fp32 -> bf16 in ws --------
__global__ __launch_bounds__(TPB) void k0_cvt(
    const float* __restrict__ inw, const float* __restrict__ inb,
    const float* __restrict__ outw, const float* __restrict__ outb,
    const float* __restrict__ n1w, const float* __restrict__ n1b,
    const float* __restrict__ n2w, const float* __restrict__ n2b,
    const float* __restrict__ w1, const float* __restrict__ b1,
    const float* __restrict__ w2, const float* __restrict__ b2,
    unsigned short* __restrict__ dst)
{
    int i = blockIdx.x * TPB + threadIdx.x;
    if (i >= 1183872) return;
    const float* src; int off;
    if      (i < 442368)  { src = inw;  off = 0; }
    else if (i < 443520)  { src = inb;  off = 442368; }
    else if (i < 590976)  { src = outw; off = 443520; }
    else if (i < 591360)  { src = outb; off = 590976; }
    else if (i < 591744)  { src = n1w;  off = 591360; }
    else if (i < 592128)  { src = n1b;  off = 591744; }
    else if (i < 592512)  { src = n2w;  off = 592128; }
    else if (i < 592896)  { src = n2b;  off = 592512; }
    else if (i < 887808)  { src = w1;   off = 592896; }
    else if (i < 888576)  { src = b1;   off = 887808; }
    else if (i < 1183488) { src = w2;   off = 888576; }
    else                  { src = b2;   off = 1183488; }
    dst[i] = f2bf(src[i - off]);
}

// ---------------- K2: LN1 + attention + out-proj + residual, fused ---------
// 512 threads = 8 waves. Wave h owns head h. 3 barriers total.
// LDS: ylds 48KB (x-window -> y -> dead) + 8 x 12KB per-wave scratch = 144KB.
__global__ __launch_bounds__(512) void k2_attn(
    const float* __restrict__ x,
    unsigned short* __restrict__ yo,        // out: win2 = x + out_proj(attn)
    const unsigned short* __restrict__ n1w,
    const unsigned short* __restrict__ n1b,
    const unsigned short* __restrict__ in_w,
    const unsigned short* __restrict__ in_b,
    const unsigned short* __restrict__ out_w,
    const unsigned short* __restrict__ out_b)
{
    __shared__ __align__(16) unsigned short ylds[24576];
    __shared__ __align__(16) unsigned short wbuf[8][6144];
    const int tid = threadIdx.x;
    const int h = tid >> 6, lane = tid & 63;
    const int l15 = lane & 15, lg = lane >> 4;
    const int widx = blockIdx.x;
    const int b = widx >> 8, nh = (widx >> 4) & 15, nw = widx & 15;
    const size_t base = (size_t)widx * 24576;
    const size_t xbase = (size_t)b * 384 * 16384 + (size_t)nh * 8 * 128 + (size_t)nw * 8;
    const short8 z8 = {0, 0, 0, 0, 0, 0, 0, 0};

    unsigned short* bufA = &wbuf[h][0];     // Q -> P halves -> O (head slice)
    unsigned short* bufB = &wbuf[h][3072];  // K -> V^T

    // ---- Phase A: stage x window -> ylds (bf16, XOR-swizzled) ----
    for (int idx = tid; idx < 6144; idx += 512) {
        int c = idx >> 4, i = (idx >> 1) & 7, half = idx & 1;
        floatx4 v = *(const floatx4*)(x + xbase + (size_t)c * 16384 + i * 128 + half * 4);
        #pragma unroll
        for (int j = 0; j < 4; ++j) {
            int m = i * 8 + half * 4 + j;
            ylds[m * 384 + (((c >> 3) ^ (m & 7)) << 3) + (c & 7)] = f2bf(v[j]);
        }
    }
    __syncthreads();

    // ---- Phase A2: LN1 in place (8 threads/row, wave-synchronous) ----
    {
        int row = tid >> 3, part = tid & 7;
        float s = 0.f, sq = 0.f;
        #pragma unroll
        for (int g = 0; g < 6; ++g) {
            int ck = part * 6 + g;
            short8 v = *(const short8*)&ylds[row * 384 + ((ck ^ (row & 7)) << 3)];
            #pragma unroll
            for (int j = 0; j < 8; ++j) { float f = bf2f((unsigned short)v[j]); s += f; sq += f * f; }
        }
        s += __shfl_xor(s, 1); s += __shfl_xor(s, 2); s += __shfl_xor(s, 4);
        sq += __shfl_xor(sq, 1); sq += __shfl_xor(sq, 2); sq += __shfl_xor(sq, 4);
        float mu = s * (1.f / 384.f);
        float rs = rsqrtf(sq * (1.f / 384.f) - mu * mu + 1e-5f);
        #pragma unroll
        for (int g = 0; g < 6; ++g) {
            int ck = part * 6 + g;
            unsigned short* p = &ylds[row * 384 + ((ck ^ (row & 7)) << 3)];
            short8 v = *(const short8*)p;
            short8 wv = *(const short8*)(n1w + ck * 8);
            short8 bv = *(const short8*)(n1b + ck * 8);
            short8 o;
            #pragma unroll
            for (int j = 0; j < 8; ++j)
                o[j] = (short)f2bf((bf2f((unsigned short)v[j]) - mu) * rs *
                                   bf2f((unsigned short)wv[j]) + bf2f((unsigned short)bv[j]));
            *(short8*)p = o;
        }
    }
    __syncthreads();

    const float scale = 0.14433756729740643f;  // 1/sqrt(48)
    const unsigned short* wq = in_w + (size_t)(h * 48) * 384;
    const unsigned short* wk = in_w + (size_t)(384 + h * 48) * 384;
    const unsigned short* wv = in_w + (size_t)(768 + h * 48) * 384;

    // ---- Q,K projection (64x48 each, K=384), into per-wave LDS ----
    {
        floatx4 acc[4][6];
        #pragma unroll
        for (int mt = 0; mt < 4; ++mt)
            #pragma unroll
            for (int i = 0; i < 6; ++i) acc[mt][i] = (floatx4){0, 0, 0, 0};
        #pragma unroll 1
        for (int ks = 0; ks < 12; ++ks) {
            short8 a[4];
            #pragma unroll
            for (int mt = 0; mt < 4; ++mt) {
                int m = mt * 16 + l15;
                a[mt] = *(const short8*)&ylds[m * 384 + (((ks * 4 + lg) ^ (m & 7)) << 3)];
            }
            #pragma unroll
            for (int nt = 0; nt < 3; ++nt) {
                short8 bq = *(const short8*)(wq + (size_t)(nt * 16 + l15) * 384 + ks * 32 + lg * 8);
                #pragma unroll
                for (int mt = 0; mt < 4; ++mt) acc[mt][nt] = mfma16(a[mt], bq, acc[mt][nt]);
                short8 bk = *(const short8*)(wk + (size_t)(nt * 16 + l15) * 384 + ks * 32 + lg * 8);
                #pragma unroll
                for (int mt = 0; mt < 4; ++mt) acc[mt][3 + nt] = mfma16(a[mt], bk, acc[mt][3 + nt]);
            }
        }
        #pragma unroll
        for (int sel = 0; sel < 2; ++sel) {
            unsigned short* dst = sel ? bufB : bufA;
            #pragma unroll
            for (int nt = 0; nt < 3; ++nt) {
                int d = nt * 16 + l15;
                int g = d >> 3;
                float bias = bf2f(in_b[sel * 384 + h * 48 + d]);
                #pragma unroll
                for (int mt = 0; mt < 4; ++mt)
                    #pragma unroll
                    for (int r = 0; r < 4; ++r) {
                        int mm = mt * 16 + lg * 4 + r;
                        dst[mm * 48 + ((g ^ (mm & 1)) << 3) + (d & 7)] =
                            f2bf(acc[mt][sel * 3 + nt][r] + bias);
                    }
            }
        }
    }

    // ---- S = Q K^T ----
    floatx4 sacc[4][4];
    #pragma unroll
    for (int mt = 0; mt < 4; ++mt)
        #pragma unroll
        for (int nt = 0; nt < 4; ++nt) sacc[mt][nt] = (floatx4){0, 0, 0, 0};
    {
        short8 b0[4], b1[4];
        #pragma unroll
        for (int nt = 0; nt < 4; ++nt) {
            int n = nt * 16 + l15;
            b0[nt] = *(const short8*)&bufB[n * 48 + ((lg ^ (n & 1)) << 3)];
            b1[nt] = (lg < 2) ? *(const short8*)&bufB[n * 48 + (((4 + lg) ^ (n & 1)) << 3)] : z8;
        }
        #pragma unroll
        for (int mt = 0; mt < 4; ++mt) {
            int mq = mt * 16 + l15;
            short8 a0 = *(const short8*)&bufA[mq * 48 + ((lg ^ (mq & 1)) << 3)];
            #pragma unroll
            for (int nt = 0; nt < 4; ++nt) sacc[mt][nt] = mfma16(a0, b0[nt], sacc[mt][nt]);
            short8 a1 = (lg < 2) ? *(const short8*)&bufA[mq * 48 + (((4 + lg) ^ (mq & 1)) << 3)] : z8;
            #pragma unroll
            for (int nt = 0; nt < 4; ++nt) sacc[mt][nt] = mfma16(a1, b1[nt], sacc[mt][nt]);
        }
    }

    // ---- softmax, fully in-register ----
    #pragma unroll
    for (int mt = 0; mt < 4; ++mt)
        #pragma unroll
        for (int r = 0; r < 4; ++r) {
            float mx = fmaxf(fmaxf(sacc[mt][0][r], sacc[mt][1][r]),
                             fmaxf(sacc[mt][2][r], sacc[mt][3][r]));
            mx = fmaxf(mx, __shfl_xor(mx, 1));
            mx = fmaxf(mx, __shfl_xor(mx, 2));
            mx = fmaxf(mx, __shfl_xor(mx, 4));
            mx = fmaxf(mx, __shfl_xor(mx, 8));
            float e[4];
            #pragma unroll
            for (int nt = 0; nt < 4; ++nt) e[nt] = __expf(scale * (sacc[mt][nt][r] - mx));
            float sm = e[0] + e[1] + e[2] + e[3];
            sm += __shfl_xor(sm, 1); sm += __shfl_xor(sm, 2);
            sm += __shfl_xor(sm, 4); sm += __shfl_xor(sm, 8);
            float inv = 1.f / sm;
            #pragma unroll
            for (int nt = 0; nt < 4; ++nt) sacc[mt][nt][r] = e[nt] * inv;
        }

    // ---- store P half 0 into bufA (Q dead) ----
    #pragma unroll
    for (int mt = 0; mt < 4; ++mt)
        #pragma unroll
        for (int r = 0; r < 4; ++r) {
            int row = mt * 16 + lg * 4 + r;
            #pragma unroll
            for (int ntl = 0; ntl < 2; ++ntl) {
                int lc = ntl * 16 + l15;
                bufA[row * 32 + (((lc >> 3) ^ (row & 3)) << 3) + (lc & 7)] =
                    f2bf(sacc[mt][ntl][r]);
            }
        }

    // ---- V projection ----
    floatx4 vacc[4][3];
    #pragma unroll
    for (int mt = 0; mt < 4; ++mt)
        #pragma unroll
        for (int nt = 0; nt < 3; ++nt) vacc[mt][nt] = (floatx4){0, 0, 0, 0};
    #pragma unroll 1
    for (int ks = 0; ks < 12; ++ks) {
        short8 a[4];
        #pragma unroll
        for (int mt = 0; mt < 4; ++mt) {
            int m = mt * 16 + l15;
            a[mt] = *(const short8*)&ylds[m * 384 + (((ks * 4 + lg) ^ (m & 7)) << 3)];
        }
        #pragma unroll
        for (int nt = 0; nt < 3; ++nt) {
            short8 bv = *(const short8*)(wv + (size_t)(nt * 16 + l15) * 384 + ks * 32 + lg * 8);
            #pragma unroll
            for (int mt = 0; mt < 4; ++mt) vacc[mt][nt] = mfma16(a[mt], bv, vacc[mt][nt]);
        }
    }
    // V^T [48][64] swizzled into bufB (K dead)
    #pragma unroll
    for (int nt = 0; nt < 3; ++nt) {
        int d = nt * 16 + l15;
        float bias = bf2f(in_b[768 + h * 48 + d]);
        #pragma unroll
        for (int mt = 0; mt < 4; ++mt)
            #pragma unroll
            for (int r = 0; r < 4; ++r) {
                int t = mt * 16 + lg * 4 + r;
                bufB[d * 64 + (((t >> 3) ^ (d & 7)) << 3) + (t & 7)] =
                    f2bf(vacc[mt][nt][r] + bias);
            }
    }

    // ---- O = P V (K=64 in two halves; P half 1 stored mid-loop) ----
    floatx4 oacc[4][3];
    #pragma unroll
    for (int mt = 0; mt < 4; ++mt)
        #pragma unroll
        for (int nt = 0; nt < 3; ++nt) oacc[mt][nt] = (floatx4){0, 0, 0, 0};
    #pragma unroll
    for (int kh = 0; kh < 2; ++kh) {
        if (kh == 1) {
            #pragma unroll
            for (int mt = 0; mt < 4; ++mt)
                #pragma unroll
                for (int r = 0; r < 4; ++r) {
                    int row = mt * 16 + lg * 4 + r;
                    #pragma unroll
                    for (int ntl = 0; ntl < 2; ++ntl) {
                        int lc = ntl * 16 + l15;
                        bufA[row * 32 + (((lc >> 3) ^ (row & 3)) << 3) + (lc & 7)] =
                            f2bf(sacc[mt][2 + ntl][r]);
                    }
                }
        }
        #pragma unroll
        for (int mt = 0; mt < 4; ++mt) {
            int m = mt * 16 + l15;
            short8 a = *(const short8*)&bufA[m * 32 + ((lg ^ (m & 3)) << 3)];
            #pragma unroll
            for (int nt = 0; nt < 3; ++nt) {
                int d = nt * 16 + l15;
                int tg = kh * 4 + lg;
                short8 bb = *(const short8*)&bufB[d * 64 + ((tg ^ (d & 7)) << 3)];
                oacc[mt][nt] = mfma16(a, bb, oacc[mt][nt]);
            }
        }
    }
    // ---- O head-slice -> own bufA (Q-store layout) ----
    #pragma unroll
    for (int nt = 0; nt < 3; ++nt)
        #pragma unroll
        for (int mt = 0; mt < 4; ++mt)
            #pragma unroll
            for (int r = 0; r < 4; ++r) {
                int mm = mt * 16 + lg * 4 + r;
                int d = nt * 16 + l15;
                bufA[mm * 48 + (((d >> 3) ^ (mm & 1)) << 3) + (d & 7)] =
                    f2bf(oacc[mt][nt][r]);
            }
    __syncthreads();

    // ---- Phase C: out-proj (K=384 gathered from 8 head bufs) + residual ----
    {
        floatx4 acc[3][4];
        #pragma unroll
        for (int nt = 0; nt < 3; ++nt)
            #pragma unroll
            for (int mt = 0; mt < 4; ++mt) acc[nt][mt] = (floatx4){0, 0, 0, 0};
        #pragma unroll 1
        for (int ks = 0; ks < 12; ++ks) {
            int col8 = ks * 4 + lg;                 // global 8-col chunk 0..47
            int hh = (col8 * 43) >> 8;              // /6
            int lc = col8 - hh * 6;                 // %6
            short8 a[4];
            #pragma unroll
            for (int mt = 0; mt < 4; ++mt) {
                int m = mt * 16 + l15;
                a[mt] = *(const short8*)&wbuf[hh][m * 48 + ((lc ^ (m & 1)) << 3)];
            }
            #pragma unroll
            for (int nt = 0; nt < 3; ++nt) {
                int f = h * 48 + nt * 16 + l15;
                short8 bb = *(const short8*)(out_w + (size_t)f * 384 + ks * 32 + lg * 8);
                #pragma unroll
                for (int mt = 0; mt < 4; ++mt)
                    acc[nt][mt] = mfma16(a[mt], bb, acc[nt][mt]);
            }
        }
        #pragma unroll
        for (int nt = 0; nt < 3; ++nt) {
            int col = h * 48 + nt * 16 + l15;
            float bias = bf2f(out_b[col]);
            #pragma unroll
            for (int mt = 0; mt < 4; ++mt) {
                #pragma unroll
                for (int r = 0; r < 4; ++r) {
                    int m = mt * 16 + lg * 4 + r;
                    int i = m >> 3, j = m & 7;
                    float res = x[xbase + (size_t)col * 16384 + i * 128 + j];
                    yo[base + (size_t)m * 384 + col] = f2bf(acc[nt][mt][r] + bias + res);
                }
            }
        }
    }
}

// ---------------- K4: LN2 + MLP (chunked split-K) + residual, in-place ------
// 512 threads, 8 waves. LDS = ylds 48KB + h-chunk 32KB = exactly 80KB -> 2 blk/CU.
// 3 chunks of 256 hidden cols; fc2 accumulates split-K into persistent acc2.
__global__ __launch_bounds__(512, 4) void k4_mlp(
    unsigned short* __restrict__ wbuf,
    const unsigned short* __restrict__ n2w,
    const unsigned short* __restrict__ n2b,
    const unsigned short* __restrict__ w1,
    const unsigned short* __restrict__ b1,
    const unsigned short* __restrict__ w2,
    const unsigned short* __restrict__ b2)
{
    __shared__ __align__(16) unsigned short ylds[24576];  // [64][384] swz
    __shared__ __align__(16) unsigned short hch[16384];   // [64][256] swz
    const int tid = threadIdx.x;
    const int wave = tid >> 6, lane = tid & 63;
    const int l15 = lane & 15, lg = lane >> 4;
    const int widx = blockIdx.x;
    const size_t base = (size_t)widx * 24576;

    {   // LN2 from global, write swizzled ylds
        int row = tid >> 3, part = tid & 7;
        const unsigned short* src = wbuf + base + row * 384 + part * 48;
        float s = 0.f, sq = 0.f;
        #pragma unroll
        for (int g = 0; g < 6; ++g) {
            short8 v = *(const short8*)(src + g * 8);
            #pragma unroll
            for (int j = 0; j < 8; ++j) { float f = bf2f((unsigned short)v[j]); s += f; sq += f * f; }
        }
        s += __shfl_xor(s, 1); s += __shfl_xor(s, 2); s += __shfl_xor(s, 4);
        sq += __shfl_xor(sq, 1); sq += __shfl_xor(sq, 2); sq += __shfl_xor(sq, 4);
        float mu = s * (1.f / 384.f);
        float rs = rsqrtf(sq * (1.f / 384.f) - mu * mu + 1e-5f);
        #pragma unroll
        for (int g = 0; g < 6; ++g) {
            int ck = part * 6 + g;
            short8 v = *(const short8*)(src + g * 8);
            short8 wv = *(const short8*)(n2w + ck * 8);
            short8 bv = *(const short8*)(n2b + ck * 8);
            short8 o;
            #pragma unroll
            for (int j = 0; j < 8; ++j)
                o[j] = (short)f2bf((bf2f((unsigned short)v[j]) - mu) * rs *
                                   bf2f((unsigned short)wv[j]) + bf2f((unsigned short)bv[j]));
            *(short8*)&ylds[row * 384 + ((ck ^ (row & 7)) << 3)] = o;
        }
    }
    __syncthreads();

    floatx4 acc2[12];
    #pragma unroll
    for (int i = 0; i < 12; ++i) acc2[i] = (floatx4){0, 0, 0, 0};

    #pragma unroll 1
    for (int cc = 0; cc < 3; ++cc) {
        // fc1 chunk: wave computes 32 hidden cols (2 n-tiles) x 64 tokens
        floatx4 acc[8];
        #pragma unroll
        for (int i = 0; i < 8; ++i) acc[i] = (floatx4){0, 0, 0, 0};
        #pragma unroll 1
        for (int ks = 0; ks < 12; ++ks) {
            short8 a[4];
            #pragma unroll
            for (int mt = 0; mt < 4; ++mt) {
                int m = mt * 16 + l15;
                a[mt] = *(const short8*)&ylds[m * 384 + (((ks * 4 + lg) ^ (m & 7)) << 3)];
            }
            #pragma unroll
            for (int nt = 0; nt < 2; ++nt) {
                int f = cc * 256 + wave * 32 + nt * 16 + l15;
                short8 bb = *(const short8*)(w1 + (size_t)f * 384 + ks * 32 + lg * 8);
                #pragma unroll
                for (int mt = 0; mt < 4; ++mt)
                    acc[nt * 4 + mt] = mfma16(a[mt], bb, acc[nt * 4 + mt]);
            }
        }
        // GELU -> hch [token][256] swizzled
        #pragma unroll
        for (int nt = 0; nt < 2; ++nt) {
            int dloc = wave * 32 + nt * 16 + l15;
            float bias = bf2f(b1[cc * 256 + dloc]);
            #pragma unroll
            for (int mt = 0; mt < 4; ++mt) {
                #pragma unroll
                for (int r = 0; r < 4; ++r) {
                    int t = mt * 16 + lg * 4 + r;
                    float v = acc[nt * 4 + mt][r] + bias;
                    float g = 0.5f * v * (1.f + erff(v * 0.70710678118654752f));
                    hch[t * 256 + (((dloc >> 3) ^ (t & 7)) << 3) + (dloc & 7)] = f2bf(g);
                }
            }
        }
        __syncthreads();
        // fc2 partial: K = 256 of this chunk
        #pragma unroll 1
        for (int ks = 0; ks < 8; ++ks) {
            short8 a[4];
            #pragma unroll
            for (int mt = 0; mt < 4; ++mt) {
                int m = mt * 16 + l15;
                a[mt] = *(const short8*)&hch[m * 256 + (((ks * 4 + lg) ^ (m & 7)) << 3)];
            }
            #pragma unroll
            for (int nt = 0; nt < 3; ++nt) {
                int c = wave * 48 + nt * 16 + l15;
                short8 bb = *(const short8*)(w2 + (size_t)c * 768 + cc * 256 + ks * 32 + lg * 8);
                #pragma unroll
                for (int mt = 0; mt < 4; ++mt)
                    acc2[nt * 4 + mt] = mfma16(a[mt], bb, acc2[nt * 4 + mt]);
            }
        }
        __syncthreads();
    }

    #pragma unroll
    for (int nt = 0; nt < 3; ++nt) {
        int col = wave * 48 + nt * 16 + l15;
        float bias = bf2f(b2[col]);
        #pragma unroll
        for (int mt = 0; mt < 4; ++mt) {
            #pragma unroll
            for (int r = 0; r < 4; ++r) {
                int mm = mt * 16 + lg * 4 + r;
                float res = bf2f(wbuf[base + (size_t)mm * 384 + col]);
                wbuf[base + (size_t)mm * 384 + col] = f2bf(acc2[nt * 4 + mt][r] + bias + res);
            }
        }
    }
}

// ---------------- K5: window reverse, bf16 window-major -> fp32 [b,c,h,w] ---
__global__ __launch_bounds__(TPB) void k5_out(
    const unsigned short* __restrict__ res,
    float* __restrict__ out)
{
    __shared__ __align__(16) unsigned short t[128][200];
    const int tid = threadIdx.x;
    const int bid = blockIdx.x;
    const int ch = bid & 1, i = (bid >> 1) & 7, nh = (bid >> 4) & 15, b = bid >> 8;

    {
        int wrow = tid >> 1, half = tid & 1;
        int nw = wrow >> 3, j = wrow & 7;
        size_t rbase = (size_t)(((b * 16 + nh) * 16) + nw) * 24576 + (i * 8 + j) * 384 + ch * 192;
        #pragma unroll
        for (int g = 0; g < 12; ++g) {
            int cc = half * 12 + g;
            short8 v = *(const short8*)(res + rbase + cc * 8);
            *(short8*)&t[wrow][cc * 8] = v;
        }
    }
    __syncthreads();
    {
        int q = tid >> 5, wg = tid & 31;
        int w0 = wg * 4;
        size_t obase = ((size_t)b * 384 + ch * 192) * 16384 + (size_t)(nh * 8 + i) * 128 + w0;
        #pragma unroll 1
        for (int cc = 0; cc < 24; ++cc) {
            int cp = cc * 8 + q;
            floatx4 v;
            #pragma unroll
            for (int k = 0; k < 4; ++k) v[k] = bf2f(t[w0 + k][cp]);
            *(floatx4*)(out + obase + (size_t)cp * 16384) = v;
        }
    }
}

extern "C" void kernel_launch(void* const* d_in, const int* in_sizes, int n_in,
                              void* d_out, int out_size, void* d_ws, size_t ws_size,
                              hipStream_t stream) {
    (void)in_sizes; (void)n_in; (void)out_size; (void)ws_size;
    const float* x    = (const float*)d_in[0];
    const float* n1w  = (const float*)d_in[1];
    const float* n1b  = (const float*)d_in[2];
    const float* inw  = (const float*)d_in[3];
    const float* inb  = (const float*)d_in[4];
    const float* outw = (const float*)d_in[5];
    const float* outb = (const float*)d_in[6];
    const float* n2w  = (const float*)d_in[7];
    const float* n2b  = (const float*)d_in[8];
    const float* w1   = (const float*)d_in[9];
    const float* b1   = (const float*)d_in[10];
    const float* w2   = (const float*)d_in[11];
    const float* b2   = (const float*)d_in[12];
    unsigned short* wsu  = (unsigned short*)d_ws;
    unsigned short* ybuf = wsu;                      // win-major activations
    unsigned short* wb   = wsu + 50331648;           // bf16 weights
    const unsigned short* inw_b  = wb;
    const unsigned short* inb_b  = wb + 442368;
    const unsigned short* outw_b = wb + 443520;
    const unsigned short* outb_b = wb + 590976;
    const unsigned short* n1w_b  = wb + 591360;
    const unsigned short* n1b_b  = wb + 591744;
    const unsigned short* n2w_b  = wb + 592128;
    const unsigned short* n2b_b  = wb + 592512;
    const unsigned short* w1_b   = wb + 592896;
    const unsigned short* b1_b   = wb + 887808;
    const unsigned short* w2_b   = wb + 888576;
    const unsigned short* b2_b   = wb + 1183488;
    float* out = (float*)d_out;

    k0_cvt<<<dim3((1183872 + TPB - 1) / TPB), dim3(TPB), 0, stream>>>(
        inw, inb, outw, outb, n1w, n1b, n2w, n2b, w1, b1, w2, b2, wb);
    k2_attn<<<dim3(NWIN), dim3(512), 0, stream>>>(
        x, ybuf, n1w_b, n1b_b, inw_b, inb_b, outw_b, outb_b);
    k4_mlp<<<dim3(NWIN), dim3(512), 0, stream>>>(ybuf, n2w_b, n2b_b, w1_b, b1_b, w2_b, b2_b);
    k5_out<<<dim3(NWIN), dim3(TPB), 0, stream>>>(ybuf, out);
}